// Round 1
// baseline (48.241 us; speedup 1.0000x reference)
//
#include <hip/hip_runtime.h>
#include <math.h>

#define EPS_F 1e-10f

// sanitize like jnp.nan_to_num(nan=eps, posinf=eps, neginf=eps) then abs
__device__ __forceinline__ float san(float v) {
  return isfinite(v) ? fabsf(v) : EPS_F;
}

// logm of a symmetric 3x3 (entries already sanitized), eigenvector-free.
// Output L = unique entries [m00, m01, m02, m11, m12, m22].
__device__ __forceinline__ void logm3(float a00, float a01, float a02,
                                      float a11, float a12, float a22,
                                      float L[6]) {
  const float q   = (a00 + a11 + a22) * (1.0f / 3.0f);
  const float b00 = a00 - q, b11 = a11 - q, b22 = a22 - q;
  const float p2  = b00 * b00 + b11 * b11 + b22 * b22 +
                    2.0f * (a01 * a01 + a02 * a02 + a12 * a12);

  float amax = fmaxf(fmaxf(fabsf(a00), fabsf(a11)), fabsf(a22));
  amax = fmaxf(amax, fmaxf(fmaxf(fabsf(a01), fabsf(a02)), fabsf(a12)));

  const float p = sqrtf(p2 * (1.0f / 6.0f));

  // near-isotropic: A ~= q I  (also guards all divisions below, since
  // the extreme eigenvalue spread g13 >= 2p)
  if (p <= 1e-5f * amax + 1e-30f) {
    const float fq = logf(q + EPS_F) + EPS_F;
    L[0] = fq; L[1] = 0.0f; L[2] = 0.0f;
    L[3] = fq; L[4] = 0.0f; L[5] = fq;
    return;
  }

  // Smith's trigonometric eigenvalues for symmetric 3x3
  const float pinv = 1.0f / p;
  const float d00 = b00 * pinv, d11 = b11 * pinv, d22 = b22 * pinv;
  const float o01 = a01 * pinv, o02 = a02 * pinv, o12 = a12 * pinv;
  const float detB = d00 * (d11 * d22 - o12 * o12)
                   - o01 * (o01 * d22 - o12 * o02)
                   + o02 * (o01 * o12 - d11 * o02);
  float r = detB * 0.5f;
  r = fminf(1.0f, fmaxf(-1.0f, r));
  const float phi = acosf(r) * (1.0f / 3.0f);
  const float l1 = q + 2.0f * p * cosf(phi);                      // largest
  const float l3 = q + 2.0f * p * cosf(phi + 2.0943951023931953f); // smallest
  const float l2 = 3.0f * q - l1 - l3;

  // A^2 (symmetric)
  const float s00 = a00 * a00 + a01 * a01 + a02 * a02;
  const float s01 = a00 * a01 + a01 * a11 + a02 * a12;
  const float s02 = a00 * a02 + a01 * a12 + a02 * a22;
  const float s11 = a01 * a01 + a11 * a11 + a12 * a12;
  const float s12 = a01 * a02 + a11 * a12 + a12 * a22;
  const float s22 = a02 * a02 + a12 * a12 + a22 * a22;

  // choose the isolated extreme eigenvalue alpha; beta = middle; gamma = other extreme
  const float g12 = l1 - l2, g23 = l2 - l3;
  float alpha, gamma;
  if (g12 >= g23) { alpha = l1; gamma = l3; }
  else            { alpha = l3; gamma = l1; }
  const float beta = l2;

  const float f_a = logf(alpha + EPS_F) + EPS_F;
  const float f_b = logf(beta  + EPS_F) + EPS_F;
  const float f_g = logf(gamma + EPS_F) + EPS_F;

  // P_alpha = (A - beta I)(A - gamma I) / ((alpha-beta)(alpha-gamma))
  const float inv_den_a = 1.0f / ((alpha - beta) * (alpha - gamma));
  const float sbg = beta + gamma, pbg = beta * gamma;
  const float pa00 = (s00 - sbg * a00 + pbg) * inv_den_a;
  const float pa01 = (s01 - sbg * a01)       * inv_den_a;
  const float pa02 = (s02 - sbg * a02)       * inv_den_a;
  const float pa11 = (s11 - sbg * a11 + pbg) * inv_den_a;
  const float pa12 = (s12 - sbg * a12)       * inv_den_a;
  const float pa22 = (s22 - sbg * a22 + pbg) * inv_den_a;

  // N = (A - alpha I)(A - beta I)
  const float sab = alpha + beta, pab = alpha * beta;
  const float n00 = s00 - sab * a00 + pab;
  const float n01 = s01 - sab * a01;
  const float n02 = s02 - sab * a02;
  const float n11 = s11 - sab * a11 + pab;
  const float n12 = s12 - sab * a12;
  const float n22 = s22 - sab * a22 + pab;

  // stable divided difference of f over the close pair (beta, gamma)
  const float gap = gamma - beta;
  float dd;
  if (fabsf(gap) > 1e-5f * fmaxf(fabsf(beta), fabsf(gamma))) {
    dd = (f_g - f_b) / gap;
  } else {
    dd = 1.0f / (0.5f * (beta + gamma) + EPS_F);   // d/dx log(x+eps)
  }
  const float cg = dd / (gamma - alpha);

  // logm = f_b*I + (f_a - f_b)*P_alpha + cg*N
  const float w = f_a - f_b;
  L[0] = f_b + w * pa00 + cg * n00;
  L[1] =       w * pa01 + cg * n01;
  L[2] =       w * pa02 + cg * n02;
  L[3] = f_b + w * pa11 + cg * n11;
  L[4] =       w * pa12 + cg * n12;
  L[5] = f_b + w * pa22 + cg * n22;
}

__device__ __forceinline__ float pair_loss(float a0, float a1, float a2,
                                           float a4, float a5, float a8,
                                           float b0, float b1, float b2,
                                           float b4, float b5, float b8) {
  float L1[6], L2[6];
  logm3(san(a0), san(a1), san(a2), san(a4), san(a5), san(a8), L1);
  logm3(san(b0), san(b1), san(b2), san(b4), san(b5), san(b8), L2);
  const float d0 = L1[0] - L2[0];
  const float d1 = L1[1] - L2[1];
  const float d2 = L1[2] - L2[2];
  const float d3 = L1[3] - L2[3];
  const float d4 = L1[4] - L2[4];
  const float d5 = L1[5] - L2[5];
  // full 3x3 Frobenius: off-diagonals count twice
  return d0 * d0 + d3 * d3 + d5 * d5 + 2.0f * (d1 * d1 + d2 * d2 + d4 * d4);
}

__global__ void __launch_bounds__(256)
leloss_partial(const float* __restrict__ d1, const float* __restrict__ d2,
               float* __restrict__ partial, int nfull, int nmat) {
  const int t = blockIdx.x * blockDim.x + threadIdx.x;
  float acc = 0.0f;

  if (t < nfull) {
    // 4 matrix pairs per thread: 36 floats = 9 aligned float4 per tensor
    float a[36], b[36];
    const float4* p1 = reinterpret_cast<const float4*>(d1) + (size_t)t * 9;
    const float4* p2 = reinterpret_cast<const float4*>(d2) + (size_t)t * 9;
#pragma unroll
    for (int i = 0; i < 9; ++i) {
      const float4 v = p1[i];
      a[4 * i + 0] = v.x; a[4 * i + 1] = v.y;
      a[4 * i + 2] = v.z; a[4 * i + 3] = v.w;
    }
#pragma unroll
    for (int i = 0; i < 9; ++i) {
      const float4 v = p2[i];
      b[4 * i + 0] = v.x; b[4 * i + 1] = v.y;
      b[4 * i + 2] = v.z; b[4 * i + 3] = v.w;
    }
#pragma unroll
    for (int m = 0; m < 4; ++m) {
      acc += pair_loss(a[9 * m + 0], a[9 * m + 1], a[9 * m + 2],
                       a[9 * m + 4], a[9 * m + 5], a[9 * m + 8],
                       b[9 * m + 0], b[9 * m + 1], b[9 * m + 2],
                       b[9 * m + 4], b[9 * m + 5], b[9 * m + 8]);
    }
  } else if (t == nfull) {
    // scalar tail (nmat % 4 matrices) — empty for this problem size
    for (int j = 4 * nfull; j < nmat; ++j) {
      const size_t base = (size_t)j * 9;
      acc += pair_loss(d1[base + 0], d1[base + 1], d1[base + 2],
                       d1[base + 4], d1[base + 5], d1[base + 8],
                       d2[base + 0], d2[base + 1], d2[base + 2],
                       d2[base + 4], d2[base + 5], d2[base + 8]);
    }
  }

  // wave reduce (64 lanes)
#pragma unroll
  for (int off = 32; off > 0; off >>= 1) acc += __shfl_down(acc, off, 64);

  __shared__ float wsum[4];
  const int lane = threadIdx.x & 63;
  const int wid  = threadIdx.x >> 6;
  if (lane == 0) wsum[wid] = acc;
  __syncthreads();
  if (threadIdx.x == 0) {
    partial[blockIdx.x] = wsum[0] + wsum[1] + wsum[2] + wsum[3];
  }
}

__global__ void __launch_bounds__(256)
leloss_reduce(const float* __restrict__ partial, int n,
              float* __restrict__ out, double inv_count) {
  double s = 0.0;
  for (int i = threadIdx.x; i < n; i += 256) s += (double)partial[i];
#pragma unroll
  for (int off = 32; off > 0; off >>= 1) s += __shfl_down(s, off, 64);

  __shared__ double wsum[4];
  const int lane = threadIdx.x & 63;
  const int wid  = threadIdx.x >> 6;
  if (lane == 0) wsum[wid] = s;
  __syncthreads();
  if (threadIdx.x == 0) {
    const double total = wsum[0] + wsum[1] + wsum[2] + wsum[3];
    out[0] = (float)(total * inv_count);
  }
}

extern "C" void kernel_launch(void* const* d_in, const int* in_sizes, int n_in,
                              void* d_out, int out_size, void* d_ws, size_t ws_size,
                              hipStream_t stream) {
  const float* d1 = (const float*)d_in[0];
  const float* d2 = (const float*)d_in[1];
  float* out = (float*)d_out;
  float* partial = (float*)d_ws;

  const long long nelem = (long long)in_sizes[0];
  const int nmat  = (int)(nelem / 9);
  const int nfull = nmat / 4;

  const int nthreads = nfull + 1;             // +1 thread owns the scalar tail
  const int nblocks  = (nthreads + 255) / 256;

  leloss_partial<<<nblocks, 256, 0, stream>>>(d1, d2, partial, nfull, nmat);

  const double inv_count = 1.0 / ((double)nmat * 9.0);
  leloss_reduce<<<1, 256, 0, stream>>>(partial, nblocks, out, inv_count);
}

// Round 2
// 38.836 us; speedup vs baseline: 1.2422x; 1.2422x over previous
//
#include <hip/hip_runtime.h>
#include <math.h>

#define EPS_F 1e-10f

// sanitize like jnp.nan_to_num(nan=eps, posinf=eps, neginf=eps) then abs
__device__ __forceinline__ float san(float v) {
  return isfinite(v) ? fabsf(v) : EPS_F;
}

__device__ __forceinline__ float fast_log(float x) {
  // natural log via native v_log_f32 (log2), ~1 ulp
  return __logf(x);
}

// acos via minimax poly (A&S-style, |err| ~ 2e-8 rad), 1 sqrt + 8 FMA
__device__ __forceinline__ float fast_acos(float r) {
  const float t = fabsf(r);
  const float s = __builtin_amdgcn_sqrtf(1.0f - t);
  float p = -0.0012624911f;
  p = fmaf(p, t,  0.0066700901f);
  p = fmaf(p, t, -0.0170881256f);
  p = fmaf(p, t,  0.0308918810f);
  p = fmaf(p, t, -0.0501743046f);
  p = fmaf(p, t,  0.0889789874f);
  p = fmaf(p, t, -0.2145988016f);
  p = fmaf(p, t,  1.5707963050f);
  const float ac = s * p;                       // acos(|r|)
  return (r < 0.0f) ? (3.14159265358979f - ac) : ac;
}

// logm of a symmetric 3x3 (entries already sanitized), eigenvector-free.
// Output L = unique entries [m00, m01, m02, m11, m12, m22].
__device__ __forceinline__ void logm3(float a00, float a01, float a02,
                                      float a11, float a12, float a22,
                                      float L[6]) {
  const float q   = (a00 + a11 + a22) * (1.0f / 3.0f);
  const float b00 = a00 - q, b11 = a11 - q, b22 = a22 - q;
  const float p2  = b00 * b00 + b11 * b11 + b22 * b22 +
                    2.0f * (a01 * a01 + a02 * a02 + a12 * a12);

  float amax = fmaxf(fmaxf(fabsf(a00), fabsf(a11)), fabsf(a22));
  amax = fmaxf(amax, fmaxf(fmaxf(fabsf(a01), fabsf(a02)), fabsf(a12)));

  const float p = __builtin_amdgcn_sqrtf(p2 * (1.0f / 6.0f));

  // near-isotropic: A ~= q I (never taken for this data distribution; safety)
  if (p <= 1e-5f * amax + 1e-30f) {
    const float fq = fast_log(q + EPS_F) + EPS_F;
    L[0] = fq; L[1] = 0.0f; L[2] = 0.0f;
    L[3] = fq; L[4] = 0.0f; L[5] = fq;
    return;
  }

  // Smith's trigonometric eigenvalues for symmetric 3x3
  const float pinv = __builtin_amdgcn_rcpf(p);
  // det of traceless part (unnormalized), then scale by 1/(2 p^3)
  const float detB = b00 * (b11 * b22 - a12 * a12)
                   - a01 * (a01 * b22 - a12 * a02)
                   + a02 * (a01 * a12 - b11 * a02);
  float r = detB * 0.5f * pinv * pinv * pinv;
  r = fminf(1.0f, fmaxf(-1.0f, r));
  const float phi = fast_acos(r) * (1.0f / 3.0f);
  const float twop = 2.0f * p;
  const float l1 = q + twop * __cosf(phi);                         // largest
  const float l3 = q + twop * __cosf(phi + 2.0943951023931953f);   // smallest
  const float l2 = 3.0f * q - l1 - l3;

  // A^2 (symmetric)
  const float s00 = a00 * a00 + a01 * a01 + a02 * a02;
  const float s01 = a00 * a01 + a01 * a11 + a02 * a12;
  const float s02 = a00 * a02 + a01 * a12 + a02 * a22;
  const float s11 = a01 * a01 + a11 * a11 + a12 * a12;
  const float s12 = a01 * a02 + a11 * a12 + a12 * a22;
  const float s22 = a02 * a02 + a12 * a12 + a22 * a22;

  // choose the isolated extreme eigenvalue alpha; beta = middle; gamma = other extreme
  const float g12 = l1 - l2, g23 = l2 - l3;
  const bool  top = (g12 >= g23);
  const float alpha = top ? l1 : l3;
  const float gamma = top ? l3 : l1;
  const float beta  = l2;

  const float f_a = fast_log(alpha + EPS_F) + EPS_F;
  const float f_b = fast_log(beta  + EPS_F) + EPS_F;
  const float f_g = fast_log(gamma + EPS_F) + EPS_F;

  // P_alpha = (A - beta I)(A - gamma I) / ((alpha-beta)(alpha-gamma))
  const float inv_den_a = __builtin_amdgcn_rcpf((alpha - beta) * (alpha - gamma));
  const float sbg = beta + gamma, pbg = beta * gamma;
  const float pa00 = (s00 - sbg * a00 + pbg) * inv_den_a;
  const float pa01 = (s01 - sbg * a01)       * inv_den_a;
  const float pa02 = (s02 - sbg * a02)       * inv_den_a;
  const float pa11 = (s11 - sbg * a11 + pbg) * inv_den_a;
  const float pa12 = (s12 - sbg * a12)       * inv_den_a;
  const float pa22 = (s22 - sbg * a22 + pbg) * inv_den_a;

  // N = (A - alpha I)(A - beta I)
  const float sab = alpha + beta, pab = alpha * beta;
  const float n00 = s00 - sab * a00 + pab;
  const float n01 = s01 - sab * a01;
  const float n02 = s02 - sab * a02;
  const float n11 = s11 - sab * a11 + pab;
  const float n12 = s12 - sab * a12;
  const float n22 = s22 - sab * a22 + pab;

  // stable divided difference of f over the close pair (beta, gamma) — branchless
  const float gap = gamma - beta;
  const float dd_div   = (f_g - f_b) * __builtin_amdgcn_rcpf(gap);
  const float dd_deriv = __builtin_amdgcn_rcpf(0.5f * (beta + gamma) + EPS_F);
  const bool  wide = fabsf(gap) > 1e-5f * fmaxf(fabsf(beta), fabsf(gamma));
  const float dd = wide ? dd_div : dd_deriv;
  const float cg = dd * __builtin_amdgcn_rcpf(gamma - alpha);

  // logm = f_b*I + (f_a - f_b)*P_alpha + cg*N
  const float w = f_a - f_b;
  L[0] = f_b + w * pa00 + cg * n00;
  L[1] =       w * pa01 + cg * n01;
  L[2] =       w * pa02 + cg * n02;
  L[3] = f_b + w * pa11 + cg * n11;
  L[4] =       w * pa12 + cg * n12;
  L[5] = f_b + w * pa22 + cg * n22;
}

__device__ __forceinline__ float pair_loss(float a0, float a1, float a2,
                                           float a4, float a5, float a8,
                                           float b0, float b1, float b2,
                                           float b4, float b5, float b8) {
  float L1[6], L2[6];
  logm3(san(a0), san(a1), san(a2), san(a4), san(a5), san(a8), L1);
  logm3(san(b0), san(b1), san(b2), san(b4), san(b5), san(b8), L2);
  const float d0 = L1[0] - L2[0];
  const float d1 = L1[1] - L2[1];
  const float d2 = L1[2] - L2[2];
  const float d3 = L1[3] - L2[3];
  const float d4 = L1[4] - L2[4];
  const float d5 = L1[5] - L2[5];
  // full 3x3 Frobenius: off-diagonals count twice
  return d0 * d0 + d3 * d3 + d5 * d5 + 2.0f * (d1 * d1 + d2 * d2 + d4 * d4);
}

__global__ void __launch_bounds__(256)
leloss_partial(const float* __restrict__ d1, const float* __restrict__ d2,
               float* __restrict__ partial, int nfull, int nmat) {
  const int t = blockIdx.x * blockDim.x + threadIdx.x;
  float acc = 0.0f;

  if (t < nfull) {
    // 4 matrix pairs per thread: 36 floats = 9 aligned float4 per tensor
    float a[36], b[36];
    const float4* p1 = reinterpret_cast<const float4*>(d1) + (size_t)t * 9;
    const float4* p2 = reinterpret_cast<const float4*>(d2) + (size_t)t * 9;
#pragma unroll
    for (int i = 0; i < 9; ++i) {
      const float4 v = p1[i];
      a[4 * i + 0] = v.x; a[4 * i + 1] = v.y;
      a[4 * i + 2] = v.z; a[4 * i + 3] = v.w;
    }
#pragma unroll
    for (int i = 0; i < 9; ++i) {
      const float4 v = p2[i];
      b[4 * i + 0] = v.x; b[4 * i + 1] = v.y;
      b[4 * i + 2] = v.z; b[4 * i + 3] = v.w;
    }
#pragma unroll
    for (int m = 0; m < 4; ++m) {
      acc += pair_loss(a[9 * m + 0], a[9 * m + 1], a[9 * m + 2],
                       a[9 * m + 4], a[9 * m + 5], a[9 * m + 8],
                       b[9 * m + 0], b[9 * m + 1], b[9 * m + 2],
                       b[9 * m + 4], b[9 * m + 5], b[9 * m + 8]);
    }
  } else if (t == nfull) {
    // scalar tail (nmat % 4 matrices) — empty for this problem size
    for (int j = 4 * nfull; j < nmat; ++j) {
      const size_t base = (size_t)j * 9;
      acc += pair_loss(d1[base + 0], d1[base + 1], d1[base + 2],
                       d1[base + 4], d1[base + 5], d1[base + 8],
                       d2[base + 0], d2[base + 1], d2[base + 2],
                       d2[base + 4], d2[base + 5], d2[base + 8]);
    }
  }

  // wave reduce (64 lanes)
#pragma unroll
  for (int off = 32; off > 0; off >>= 1) acc += __shfl_down(acc, off, 64);

  __shared__ float wsum[4];
  const int lane = threadIdx.x & 63;
  const int wid  = threadIdx.x >> 6;
  if (lane == 0) wsum[wid] = acc;
  __syncthreads();
  if (threadIdx.x == 0) {
    partial[blockIdx.x] = wsum[0] + wsum[1] + wsum[2] + wsum[3];
  }
}

__global__ void __launch_bounds__(256)
leloss_reduce(const float* __restrict__ partial, int n,
              float* __restrict__ out, double inv_count) {
  double s = 0.0;
  for (int i = threadIdx.x; i < n; i += 256) s += (double)partial[i];
#pragma unroll
  for (int off = 32; off > 0; off >>= 1) s += __shfl_down(s, off, 64);

  __shared__ double wsum[4];
  const int lane = threadIdx.x & 63;
  const int wid  = threadIdx.x >> 6;
  if (lane == 0) wsum[wid] = s;
  __syncthreads();
  if (threadIdx.x == 0) {
    const double total = wsum[0] + wsum[1] + wsum[2] + wsum[3];
    out[0] = (float)(total * inv_count);
  }
}

extern "C" void kernel_launch(void* const* d_in, const int* in_sizes, int n_in,
                              void* d_out, int out_size, void* d_ws, size_t ws_size,
                              hipStream_t stream) {
  const float* d1 = (const float*)d_in[0];
  const float* d2 = (const float*)d_in[1];
  float* out = (float*)d_out;
  float* partial = (float*)d_ws;

  const long long nelem = (long long)in_sizes[0];
  const int nmat  = (int)(nelem / 9);
  const int nfull = nmat / 4;

  const int nthreads = nfull + 1;             // +1 thread owns the scalar tail
  const int nblocks  = (nthreads + 255) / 256;

  leloss_partial<<<nblocks, 256, 0, stream>>>(d1, d2, partial, nfull, nmat);

  const double inv_count = 1.0 / ((double)nmat * 9.0);
  leloss_reduce<<<1, 256, 0, stream>>>(partial, nblocks, out, inv_count);
}